// Round 1
// baseline (139.919 us; speedup 1.0000x reference)
//
#include <hip/hip_runtime.h>

// VQ-VAE quantizer, faithful to the reference's buggy distance (no -2*z.e term):
//   distances[n,k] = ||z_n||^2 + ||e_k||^2  -> argmin over k is (mod fp32 tie
//   rounding, which moves z_q by <= 0.004 << 0.04 threshold) the globally
//   smallest-norm embedding row. So: one argmin, broadcast row, fused loss.
//
// Outputs (concat): z_q [32*128*64*64] f32, vq_loss [1] f32.

#define NZ   16777216   // 32*128*64*64
#define NZ4  4194304    // NZ/4
#define KEMB 512
#define CEMB 128

// ---------------- Kernel A: argmin_k ||e_k||^2, stage row, zero loss ----------
__global__ __launch_bounds__(512) void vq_prep(const float* __restrict__ emb,
                                               float* __restrict__ ws_eq,
                                               float* __restrict__ loss_ptr) {
    __shared__ float s_norm[KEMB];
    __shared__ int   s_best;

    const int t = threadIdx.x;   // one embedding row per thread
    const float4* e4 = (const float4*)emb;
    float acc = 0.f;
    #pragma unroll
    for (int i = 0; i < CEMB / 4; ++i) {
        float4 v = e4[t * (CEMB / 4) + i];
        acc += v.x * v.x + v.y * v.y + v.z * v.z + v.w * v.w;
    }
    s_norm[t] = acc;
    __syncthreads();

    if (t < 64) {
        // lane t scans rows [t*8, t*8+8) ascending; strict < keeps first min
        float bv = s_norm[t * 8];
        int   bi = t * 8;
        #pragma unroll
        for (int j = 1; j < 8; ++j) {
            float v = s_norm[t * 8 + j];
            if (v < bv) { bv = v; bi = t * 8 + j; }
        }
        // lexicographic wave reduce (val, idx) over 64 lanes
        #pragma unroll
        for (int off = 32; off > 0; off >>= 1) {
            float ov = __shfl_down(bv, off);
            int   oi = __shfl_down(bi, off);
            if (ov < bv || (ov == bv && oi < bi)) { bv = ov; bi = oi; }
        }
        if (t == 0) {
            s_best = bi;
            loss_ptr[0] = 0.f;   // d_out loss slot is poisoned; zero it here
        }
    }
    __syncthreads();
    if (t < CEMB) ws_eq[t] = emb[s_best * CEMB + t];
}

// ---------------- Kernel B: stream z_e -> z_q broadcast + fused loss ----------
__global__ __launch_bounds__(256) void vq_main(const float4* __restrict__ ze4,
                                               float4* __restrict__ zq4,
                                               const float* __restrict__ eq,
                                               float* __restrict__ loss_ptr) {
    float lsum = 0.f;
    const int stride = gridDim.x * blockDim.x;
    for (int i = blockIdx.x * blockDim.x + threadIdx.x; i < NZ4; i += stride) {
        float4 z = ze4[i];
        // flat float idx = 4*i; channel chunk is 4096 floats = 1024 float4s
        int c = (i >> 10) & (CEMB - 1);
        float e = eq[c];
        float4 q = make_float4(e, e, e, e);
        zq4[i] = q;
        float d0 = e - z.x, d1 = e - z.y, d2 = e - z.z, d3 = e - z.w;
        lsum += d0 * d0 + d1 * d1 + d2 * d2 + d3 * d3;
    }
    // wave64 shuffle reduce
    #pragma unroll
    for (int off = 32; off > 0; off >>= 1) lsum += __shfl_down(lsum, off);
    __shared__ float s_w[4];
    const int lane = threadIdx.x & 63, wid = threadIdx.x >> 6;
    if (lane == 0) s_w[wid] = lsum;
    __syncthreads();
    if (threadIdx.x == 0) {
        float s = s_w[0] + s_w[1] + s_w[2] + s_w[3];
        // vq_loss = codebook + commitment = 2 * mean(sqdiff)
        atomicAdd(loss_ptr, s * (2.0f / (float)NZ));
    }
}

extern "C" void kernel_launch(void* const* d_in, const int* in_sizes, int n_in,
                              void* d_out, int out_size, void* d_ws, size_t ws_size,
                              hipStream_t stream) {
    const float* z_e = (const float*)d_in[0];
    const float* emb = (const float*)d_in[1];
    float* out      = (float*)d_out;
    float* zq       = out;            // [NZ]
    float* loss_ptr = out + NZ;       // [1]
    float* ws_eq    = (float*)d_ws;   // [CEMB] staged winning embedding row

    vq_prep<<<1, 512, 0, stream>>>(emb, ws_eq, loss_ptr);
    vq_main<<<2048, 256, 0, stream>>>((const float4*)z_e, (float4*)zq, ws_eq, loss_ptr);
}

// Round 2
// 137.127 us; speedup vs baseline: 1.0204x; 1.0204x over previous
//
#include <hip/hip_runtime.h>

// VQ-VAE quantizer, faithful to the reference's buggy distance (no -2*z.e term):
//   distances[n,k] = ||z_n||^2 + ||e_k||^2  -> argmin over k is the globally
//   smallest-norm embedding row (fp32 tie-flips move z_q by <=0.004 << 0.04).
// Pipeline: memset ws(+inf packed) -> vq_norms (512 waves, packed atomicMin)
//           -> vq_main (stream z_e, broadcast row, fused 2*mean(sqdiff) loss).
// Outputs (concat): z_q [32*128*64*64] f32, vq_loss [1] f32.

#define NZ   16777216   // 32*128*64*64
#define NZ4  4194304    // NZ/4 float4 elements
#define NTHR 524288     // 2048 blocks * 256 threads; NZ4/NTHR == 8
#define KEMB 512
#define CEMB 128

typedef float f32x4 __attribute__((ext_vector_type(4)));

// ---- Kernel A: per-row ||e_k||^2, one row per wave, packed lexicographic
//      atomicMin into ws. Also zeroes the loss accumulator slot. ----
__global__ __launch_bounds__(256) void vq_norms(const float* __restrict__ emb,
                                                unsigned long long* __restrict__ ws_min,
                                                float* __restrict__ loss_ptr) {
    const int lane = threadIdx.x & 63;
    const int wid  = threadIdx.x >> 6;
    const int row  = blockIdx.x * 4 + wid;           // 128 blocks * 4 waves = 512 rows

    const float2 v = ((const float2*)emb)[row * 64 + lane];
    float n = v.x * v.x + v.y * v.y;
    #pragma unroll
    for (int off = 32; off > 0; off >>= 1) n += __shfl_down(n, off);

    if (lane == 0) {
        // positive-float bits are order-preserving as uint; low 32 = row index
        // -> u64 min == lexicographic (norm, first index), matching jnp.argmin.
        unsigned long long packed =
            ((unsigned long long)__float_as_uint(n) << 32) | (unsigned int)row;
        atomicMin(ws_min, packed);
    }
    if (blockIdx.x == 0 && threadIdx.x == 0) loss_ptr[0] = 0.f;
}

// ---- Kernel B: stream z_e -> broadcast z_q + fused loss. 8 float4/thread,
//      all loads issued before stores (ILP), non-temporal (no reuse). ----
__global__ __launch_bounds__(256) void vq_main(const f32x4* __restrict__ ze4,
                                               f32x4* __restrict__ zq4,
                                               const float* __restrict__ emb,
                                               const unsigned long long* __restrict__ ws_min,
                                               float* __restrict__ loss_ptr) {
    const int tid = blockIdx.x * 256 + threadIdx.x;

    // chunk stride is 2^19 float4s; c uses bits 10..16 of the flat float4
    // index -> identical for all 8 chunks of this thread, wave-uniform too.
    const int c = (tid >> 10) & (CEMB - 1);
    const int best = (int)(unsigned int)(*ws_min & 0xffffffffull);
    const float e = emb[best * CEMB + c];

    f32x4 z0 = __builtin_nontemporal_load(ze4 + tid + 0 * NTHR);
    f32x4 z1 = __builtin_nontemporal_load(ze4 + tid + 1 * NTHR);
    f32x4 z2 = __builtin_nontemporal_load(ze4 + tid + 2 * NTHR);
    f32x4 z3 = __builtin_nontemporal_load(ze4 + tid + 3 * NTHR);
    f32x4 z4 = __builtin_nontemporal_load(ze4 + tid + 4 * NTHR);
    f32x4 z5 = __builtin_nontemporal_load(ze4 + tid + 5 * NTHR);
    f32x4 z6 = __builtin_nontemporal_load(ze4 + tid + 6 * NTHR);
    f32x4 z7 = __builtin_nontemporal_load(ze4 + tid + 7 * NTHR);

    const f32x4 q = {e, e, e, e};
    __builtin_nontemporal_store(q, zq4 + tid + 0 * NTHR);
    __builtin_nontemporal_store(q, zq4 + tid + 1 * NTHR);
    __builtin_nontemporal_store(q, zq4 + tid + 2 * NTHR);
    __builtin_nontemporal_store(q, zq4 + tid + 3 * NTHR);
    __builtin_nontemporal_store(q, zq4 + tid + 4 * NTHR);
    __builtin_nontemporal_store(q, zq4 + tid + 5 * NTHR);
    __builtin_nontemporal_store(q, zq4 + tid + 6 * NTHR);
    __builtin_nontemporal_store(q, zq4 + tid + 7 * NTHR);

    float lsum = 0.f;
    {
        f32x4 d;
        d = z0 - q; lsum += d.x*d.x + d.y*d.y + d.z*d.z + d.w*d.w;
        d = z1 - q; lsum += d.x*d.x + d.y*d.y + d.z*d.z + d.w*d.w;
        d = z2 - q; lsum += d.x*d.x + d.y*d.y + d.z*d.z + d.w*d.w;
        d = z3 - q; lsum += d.x*d.x + d.y*d.y + d.z*d.z + d.w*d.w;
        d = z4 - q; lsum += d.x*d.x + d.y*d.y + d.z*d.z + d.w*d.w;
        d = z5 - q; lsum += d.x*d.x + d.y*d.y + d.z*d.z + d.w*d.w;
        d = z6 - q; lsum += d.x*d.x + d.y*d.y + d.z*d.z + d.w*d.w;
        d = z7 - q; lsum += d.x*d.x + d.y*d.y + d.z*d.z + d.w*d.w;
    }

    #pragma unroll
    for (int off = 32; off > 0; off >>= 1) lsum += __shfl_down(lsum, off);
    __shared__ float s_w[4];
    const int lane = threadIdx.x & 63, wid = threadIdx.x >> 6;
    if (lane == 0) s_w[wid] = lsum;
    __syncthreads();
    if (threadIdx.x == 0) {
        float s = s_w[0] + s_w[1] + s_w[2] + s_w[3];
        atomicAdd(loss_ptr, s * (2.0f / (float)NZ));  // codebook + commitment
    }
}

extern "C" void kernel_launch(void* const* d_in, const int* in_sizes, int n_in,
                              void* d_out, int out_size, void* d_ws, size_t ws_size,
                              hipStream_t stream) {
    const float* z_e = (const float*)d_in[0];
    const float* emb = (const float*)d_in[1];
    float* out       = (float*)d_out;
    float* loss_ptr  = out + NZ;
    unsigned long long* ws_min = (unsigned long long*)d_ws;

    // ws poisoned 0xAA each call; set to 0xFFFF... so it acts as +inf for atomicMin
    hipMemsetAsync(d_ws, 0xFF, 8, stream);
    vq_norms<<<KEMB / 4 / 64 * 64, 256, 0, stream>>>(emb, ws_min, loss_ptr);
    vq_main<<<2048, 256, 0, stream>>>((const f32x4*)z_e, (f32x4*)out, emb, ws_min, loss_ptr);
}

// Round 3
// 133.490 us; speedup vs baseline: 1.0482x; 1.0272x over previous
//
#include <hip/hip_runtime.h>

// VQ-VAE quantizer, faithful to the reference's buggy distance (no -2*z.e term):
//   distances[n,k] = ||z_n||^2 + ||e_k||^2  -> argmin over k is the globally
//   smallest-norm embedding row (fp32 tie-flips move z_q by <=0.004 << 0.04
//   threshold). So: one argmin over row norms, broadcast that row, fused loss
//   vq_loss = codebook + commitment = 2 * mean((z_q - z_e)^2).
//
// Outputs (concat): z_q [32*128*64*64] f32, vq_loss [1] f32.
//
// R3 notes: plain (cached) loads/stores — z_e is L3-hot from the harness's
// restore copy and z_q fits in L3; R2's nontemporal ops forced HBM. Prep is a
// single 1024-thread block (cheap, no d_ws init dependency, fewer graph nodes).

#define NZ   16777216   // 32*128*64*64
#define NZ4  4194304    // NZ/4 float4 elements
#define NTHR 524288     // 2048 blocks * 256 threads; NZ4/NTHR == 8
#define KEMB 512
#define CEMB 128

typedef float f32x4 __attribute__((ext_vector_type(4)));

// ---- Kernel A: argmin_k ||e_k||^2 (first-index tie-break), stage winning row
//      into ws_eq, zero the loss slot. One block, 1024 threads, 2 thr/row. ----
__global__ __launch_bounds__(1024) void vq_prep(const float* __restrict__ emb,
                                                float* __restrict__ ws_eq,
                                                float* __restrict__ loss_ptr) {
    __shared__ float s_norm[KEMB];
    __shared__ int   s_best;

    const int t = threadIdx.x;
    const int r = t >> 1;          // row 0..511
    const int h = t & 1;           // half 0/1
    const f32x4* e4 = (const f32x4*)emb;

    float acc = 0.f;
    #pragma unroll
    for (int i = 0; i < 16; ++i) {
        f32x4 v = e4[r * 32 + h * 16 + i];
        acc += v.x * v.x + v.y * v.y + v.z * v.z + v.w * v.w;
    }
    acc += __shfl_xor(acc, 1);     // combine the two halves (lanes r*2, r*2+1)
    if (h == 0) s_norm[r] = acc;
    __syncthreads();

    if (t < 64) {
        // lane t scans rows [t*8, t*8+8) ascending; strict < keeps first min
        float bv = s_norm[t * 8];
        int   bi = t * 8;
        #pragma unroll
        for (int j = 1; j < 8; ++j) {
            float v = s_norm[t * 8 + j];
            if (v < bv) { bv = v; bi = t * 8 + j; }
        }
        #pragma unroll
        for (int off = 32; off > 0; off >>= 1) {
            float ov = __shfl_down(bv, off);
            int   oi = __shfl_down(bi, off);
            if (ov < bv || (ov == bv && oi < bi)) { bv = ov; bi = oi; }
        }
        if (t == 0) { s_best = bi; loss_ptr[0] = 0.f; }
    }
    __syncthreads();
    if (t < CEMB) ws_eq[t] = emb[s_best * CEMB + t];
}

// ---- Kernel B: stream z_e -> broadcast z_q + fused loss. 8 float4/thread,
//      all loads issued before stores (ILP), cached accesses (L3-friendly). ----
__global__ __launch_bounds__(256) void vq_main(const f32x4* __restrict__ ze4,
                                               f32x4* __restrict__ zq4,
                                               const float* __restrict__ ws_eq,
                                               float* __restrict__ loss_ptr) {
    const int tid = blockIdx.x * 256 + threadIdx.x;

    // chunk stride is 2^19 float4s; c uses bits 10..16 of the flat float4
    // index -> identical for all 8 chunks, and uniform across the block
    // (tid>>10 == blockIdx.x>>2), so this compiles to a scalar load.
    const int c = (tid >> 10) & (CEMB - 1);
    const float e = ws_eq[c];

    f32x4 z0 = ze4[tid + 0 * NTHR];
    f32x4 z1 = ze4[tid + 1 * NTHR];
    f32x4 z2 = ze4[tid + 2 * NTHR];
    f32x4 z3 = ze4[tid + 3 * NTHR];
    f32x4 z4 = ze4[tid + 4 * NTHR];
    f32x4 z5 = ze4[tid + 5 * NTHR];
    f32x4 z6 = ze4[tid + 6 * NTHR];
    f32x4 z7 = ze4[tid + 7 * NTHR];

    const f32x4 q = {e, e, e, e};
    zq4[tid + 0 * NTHR] = q;
    zq4[tid + 1 * NTHR] = q;
    zq4[tid + 2 * NTHR] = q;
    zq4[tid + 3 * NTHR] = q;
    zq4[tid + 4 * NTHR] = q;
    zq4[tid + 5 * NTHR] = q;
    zq4[tid + 6 * NTHR] = q;
    zq4[tid + 7 * NTHR] = q;

    float lsum = 0.f;
    {
        f32x4 d;
        d = z0 - q; lsum += d.x*d.x + d.y*d.y + d.z*d.z + d.w*d.w;
        d = z1 - q; lsum += d.x*d.x + d.y*d.y + d.z*d.z + d.w*d.w;
        d = z2 - q; lsum += d.x*d.x + d.y*d.y + d.z*d.z + d.w*d.w;
        d = z3 - q; lsum += d.x*d.x + d.y*d.y + d.z*d.z + d.w*d.w;
        d = z4 - q; lsum += d.x*d.x + d.y*d.y + d.z*d.z + d.w*d.w;
        d = z5 - q; lsum += d.x*d.x + d.y*d.y + d.z*d.z + d.w*d.w;
        d = z6 - q; lsum += d.x*d.x + d.y*d.y + d.z*d.z + d.w*d.w;
        d = z7 - q; lsum += d.x*d.x + d.y*d.y + d.z*d.z + d.w*d.w;
    }

    #pragma unroll
    for (int off = 32; off > 0; off >>= 1) lsum += __shfl_down(lsum, off);
    __shared__ float s_w[4];
    const int lane = threadIdx.x & 63, wid = threadIdx.x >> 6;
    if (lane == 0) s_w[wid] = lsum;
    __syncthreads();
    if (threadIdx.x == 0) {
        float s = s_w[0] + s_w[1] + s_w[2] + s_w[3];
        atomicAdd(loss_ptr, s * (2.0f / (float)NZ));  // codebook + commitment
    }
}

extern "C" void kernel_launch(void* const* d_in, const int* in_sizes, int n_in,
                              void* d_out, int out_size, void* d_ws, size_t ws_size,
                              hipStream_t stream) {
    const float* z_e = (const float*)d_in[0];
    const float* emb = (const float*)d_in[1];
    float* out       = (float*)d_out;
    float* loss_ptr  = out + NZ;
    float* ws_eq     = (float*)d_ws;   // [CEMB] staged winning embedding row

    vq_prep<<<1, 1024, 0, stream>>>(emb, ws_eq, loss_ptr);
    vq_main<<<2048, 256, 0, stream>>>((const f32x4*)z_e, (f32x4*)out, ws_eq, loss_ptr);
}

// Round 15
// 129.766 us; speedup vs baseline: 1.0782x; 1.0287x over previous
//
#include <hip/hip_runtime.h>

// VQ-VAE quantizer, faithful to the reference's buggy distance (no -2*z.e term):
//   distances[n,k] = ||z_n||^2 + ||e_k||^2  -> argmin over k is the globally
//   smallest-norm embedding row (fp32 tie-flips move z_q by <=0.004 << 0.04
//   threshold). One argmin over row norms, broadcast that row, fused loss
//   vq_loss = codebook + commitment = 2 * mean((z_q - z_e)^2).
//
// Outputs (concat): z_q [32*128*64*64] f32, vq_loss [1] f32.
//
// R4 (resubmit #11 after infra failures): asymmetric caching — PLAIN loads
// (z_e is partially L3-resident from the harness restore copy; keep it
// cacheable) + NONTEMPORAL stores (z_q is write-once, never re-read on device;
// streaming it to HBM avoids evicting z_e from L3 mid-kernel). R2 showed
// nt-on-both hurts; R1/R3 cached-stores only reached ~3 TB/s effective.

#define NZ   16777216   // 32*128*64*64
#define NZ4  4194304    // NZ/4 float4 elements
#define NTHR 524288     // 2048 blocks * 256 threads; NZ4/NTHR == 8
#define KEMB 512
#define CEMB 128

typedef float f32x4 __attribute__((ext_vector_type(4)));

// ---- Kernel A: argmin_k ||e_k||^2 (first-index tie-break), stage winning row
//      into ws_eq, zero the loss slot. One block, 1024 threads, 2 thr/row. ----
__global__ __launch_bounds__(1024) void vq_prep(const float* __restrict__ emb,
                                                float* __restrict__ ws_eq,
                                                float* __restrict__ loss_ptr) {
    __shared__ float s_norm[KEMB];
    __shared__ int   s_best;

    const int t = threadIdx.x;
    const int r = t >> 1;          // row 0..511
    const int h = t & 1;           // half 0/1
    const f32x4* e4 = (const f32x4*)emb;

    float acc = 0.f;
    #pragma unroll
    for (int i = 0; i < 16; ++i) {
        f32x4 v = e4[r * 32 + h * 16 + i];
        acc += v.x * v.x + v.y * v.y + v.z * v.z + v.w * v.w;
    }
    acc += __shfl_xor(acc, 1);     // combine the two halves (lanes r*2, r*2+1)
    if (h == 0) s_norm[r] = acc;
    __syncthreads();

    if (t < 64) {
        // lane t scans rows [t*8, t*8+8) ascending; strict < keeps first min
        float bv = s_norm[t * 8];
        int   bi = t * 8;
        #pragma unroll
        for (int j = 1; j < 8; ++j) {
            float v = s_norm[t * 8 + j];
            if (v < bv) { bv = v; bi = t * 8 + j; }
        }
        #pragma unroll
        for (int off = 32; off > 0; off >>= 1) {
            float ov = __shfl_down(bv, off);
            int   oi = __shfl_down(bi, off);
            if (ov < bv || (ov == bv && oi < bi)) { bv = ov; bi = oi; }
        }
        if (t == 0) { s_best = bi; loss_ptr[0] = 0.f; }
    }
    __syncthreads();
    if (t < CEMB) ws_eq[t] = emb[s_best * CEMB + t];
}

// ---- Kernel B: stream z_e -> broadcast z_q + fused loss. 8 float4/thread,
//      cached loads, nontemporal stores, all loads issued before stores. ----
__global__ __launch_bounds__(256) void vq_main(const f32x4* __restrict__ ze4,
                                               f32x4* __restrict__ zq4,
                                               const float* __restrict__ ws_eq,
                                               float* __restrict__ loss_ptr) {
    const int tid = blockIdx.x * 256 + threadIdx.x;

    // chunk stride is 2^19 float4s; c uses bits 10..16 of the flat float4
    // index -> identical for all 8 chunks, uniform across the block
    // (tid>>10 == blockIdx.x>>2) -> compiles to a scalar load.
    const int c = (tid >> 10) & (CEMB - 1);
    const float e = ws_eq[c];

    f32x4 z0 = ze4[tid + 0 * NTHR];
    f32x4 z1 = ze4[tid + 1 * NTHR];
    f32x4 z2 = ze4[tid + 2 * NTHR];
    f32x4 z3 = ze4[tid + 3 * NTHR];
    f32x4 z4 = ze4[tid + 4 * NTHR];
    f32x4 z5 = ze4[tid + 5 * NTHR];
    f32x4 z6 = ze4[tid + 6 * NTHR];
    f32x4 z7 = ze4[tid + 7 * NTHR];

    const f32x4 q = {e, e, e, e};
    __builtin_nontemporal_store(q, zq4 + tid + 0 * NTHR);
    __builtin_nontemporal_store(q, zq4 + tid + 1 * NTHR);
    __builtin_nontemporal_store(q, zq4 + tid + 2 * NTHR);
    __builtin_nontemporal_store(q, zq4 + tid + 3 * NTHR);
    __builtin_nontemporal_store(q, zq4 + tid + 4 * NTHR);
    __builtin_nontemporal_store(q, zq4 + tid + 5 * NTHR);
    __builtin_nontemporal_store(q, zq4 + tid + 6 * NTHR);
    __builtin_nontemporal_store(q, zq4 + tid + 7 * NTHR);

    float lsum = 0.f;
    {
        f32x4 d;
        d = z0 - q; lsum += d.x*d.x + d.y*d.y + d.z*d.z + d.w*d.w;
        d = z1 - q; lsum += d.x*d.x + d.y*d.y + d.z*d.z + d.w*d.w;
        d = z2 - q; lsum += d.x*d.x + d.y*d.y + d.z*d.z + d.w*d.w;
        d = z3 - q; lsum += d.x*d.x + d.y*d.y + d.z*d.z + d.w*d.w;
        d = z4 - q; lsum += d.x*d.x + d.y*d.y + d.z*d.z + d.w*d.w;
        d = z5 - q; lsum += d.x*d.x + d.y*d.y + d.z*d.z + d.w*d.w;
        d = z6 - q; lsum += d.x*d.x + d.y*d.y + d.z*d.z + d.w*d.w;
        d = z7 - q; lsum += d.x*d.x + d.y*d.y + d.z*d.z + d.w*d.w;
    }

    #pragma unroll
    for (int off = 32; off > 0; off >>= 1) lsum += __shfl_down(lsum, off);
    __shared__ float s_w[4];
    const int lane = threadIdx.x & 63, wid = threadIdx.x >> 6;
    if (lane == 0) s_w[wid] = lsum;
    __syncthreads();
    if (threadIdx.x == 0) {
        float s = s_w[0] + s_w[1] + s_w[2] + s_w[3];
        atomicAdd(loss_ptr, s * (2.0f / (float)NZ));  // codebook + commitment
    }
}

extern "C" void kernel_launch(void* const* d_in, const int* in_sizes, int n_in,
                              void* d_out, int out_size, void* d_ws, size_t ws_size,
                              hipStream_t stream) {
    const float* z_e = (const float*)d_in[0];
    const float* emb = (const float*)d_in[1];
    float* out       = (float*)d_out;
    float* loss_ptr  = out + NZ;
    float* ws_eq     = (float*)d_ws;   // [CEMB] staged winning embedding row

    vq_prep<<<1, 1024, 0, stream>>>(emb, ws_eq, loss_ptr);
    vq_main<<<2048, 256, 0, stream>>>((const f32x4*)z_e, (f32x4*)out, ws_eq, loss_ptr);
}